// Round 8
// baseline (391.514 us; speedup 1.0000x reference)
//
#include <hip/hip_runtime.h>
#include <hip/hip_bf16.h>

#define BB 8
#define NN 1024
#define FIN 256
#define FOUT 64
#define NEGV (-9000000000000000.0f)

typedef __hip_bfloat16 bf16;
typedef short bf16x8 __attribute__((ext_vector_type(8)));
typedef float f32x4 __attribute__((ext_vector_type(4)));

__device__ __forceinline__ float b2f(bf16 v) { return __bfloat162float(v); }
__device__ __forceinline__ float bu2f(unsigned short u) {
  union { unsigned int i; float f; } c;
  c.i = ((unsigned int)u) << 16;
  return c.f;
}
__device__ __forceinline__ unsigned short f2bu(float v) {
  bf16 t = __float2bfloat16(v);
  return *(unsigned short*)&t;
}

// async global->LDS, 16B per lane; LDS dest is wave-uniform base (+lane*16 by HW)
__device__ __forceinline__ void gload_lds16(const unsigned short* g,
                                            unsigned short* l) {
  __builtin_amdgcn_global_load_lds(
      (__attribute__((address_space(1))) void*)(unsigned long long)(const void*)g,
      (__attribute__((address_space(3))) void*)l, 16, 0, 0);
}

__device__ __forceinline__ float waveRedSum(float v) {
  for (int d = 32; d; d >>= 1) v += __shfl_down(v, d);
  return v;
}
__device__ __forceinline__ float waveRedMax(float v) {
  for (int d = 32; d; d >>= 1) v = fmaxf(v, __shfl_down(v, d));
  return v;
}

__device__ __forceinline__ float blockSumF(float v, float* tmp) {
  __syncthreads();
  v = waveRedSum(v);
  if ((threadIdx.x & 63) == 0) tmp[threadIdx.x >> 6] = v;
  __syncthreads();
  return tmp[0] + tmp[1] + tmp[2] + tmp[3];
}
__device__ __forceinline__ float blockMaxF(float v, float* tmp) {
  __syncthreads();
  v = waveRedMax(v);
  if ((threadIdx.x & 63) == 0) tmp[threadIdx.x >> 6] = v;
  __syncthreads();
  return fmaxf(fmaxf(tmp[0], tmp[1]), fmaxf(tmp[2], tmp[3]));
}

__global__ void k_fill(unsigned short* o, int n, unsigned short pat) {
  int i = blockIdx.x * blockDim.x + threadIdx.x;
  int stride = gridDim.x * blockDim.x;
  for (; i < n; i += stride) o[i] = pat;
}

// dtype probe + init threshold accumulators
__global__ void k_detect(const unsigned short* xu, float* flag,
                         int* thrmin, float* thrsum) {
  const int tid = threadIdx.x;
  if (tid < BB) {
    thrmin[tid] = 0x7F800000;  // +inf (diags are positive)
    thrsum[tid] = 0.f;
  }
  float mx = 0.0f, zc = 0.0f;
  for (int i = tid; i < 8192; i += 256) {
    unsigned short u = xu[i];
    float v = bu2f(u);
    if (u == 0 || u == 0x8000) zc += 1.0f;
    mx = fmaxf(mx, fabsf(v));
  }
  __shared__ float tmp[4];
  float gm = blockMaxF(mx, tmp);
  float gz = blockSumF(zc, tmp);
  if (tid == 0) flag[0] = (gm > 1.0e6f || gz > 2048.0f) ? 1.0f : 0.0f;
}

// h = x @ W per (b,n) row; sq = |h|^2; wh1 = h.a1; wh2 = h.a2
__global__ void __launch_bounds__(64) k_h(const void* xv, const void* Wv,
                                          const void* av,
                                          const float* __restrict__ flag,
                                          float* __restrict__ h,
                                          float* __restrict__ sq,
                                          float* __restrict__ wh1,
                                          float* __restrict__ wh2) {
  const int bn = blockIdx.x;
  const int o = threadIdx.x;
  const bool f32m = (flag[0] != 0.0f);
  __shared__ float xs[FIN];
  if (f32m) {
    const float* xr = (const float*)xv + (size_t)bn * FIN;
    for (int i = o; i < FIN; i += 64) xs[i] = xr[i];
  } else {
    const bf16* xr = (const bf16*)xv + (size_t)bn * FIN;
    for (int i = o; i < FIN; i += 64) xs[i] = b2f(xr[i]);
  }
  __syncthreads();
  float acc = 0.f;
  if (f32m) {
    const float* Wf = (const float*)Wv;
    for (int i = 0; i < FIN; ++i) acc += xs[i] * Wf[i * FOUT + o];
  } else {
    const bf16* Wb = (const bf16*)Wv;
    for (int i = 0; i < FIN; ++i) acc += xs[i] * b2f(Wb[i * FOUT + o]);
  }
  h[(size_t)bn * FOUT + o] = acc;
  float a1, a2;
  if (f32m) {
    a1 = ((const float*)av)[o];
    a2 = ((const float*)av)[FOUT + o];
  } else {
    a1 = b2f(((const bf16*)av)[o]);
    a2 = b2f(((const bf16*)av)[FOUT + o]);
  }
  float s = waveRedSum(acc * acc);
  float w1 = waveRedSum(acc * a1);
  float w2 = waveRedSum(acc * a2);
  if (o == 0) {
    sq[bn] = s;
    wh1[bn] = w1;
    wh2[bn] = w2;
  }
}

// batched: A_un[z][n][m] = exp(-dist), exact 1.0 diag (round-5 proven body)
__global__ void __launch_bounds__(256) k_g(const float* __restrict__ h,
                                           const float* __restrict__ sq,
                                           float* __restrict__ A) {
  const int z = blockIdx.z;
  const float* hb = h + (size_t)z * NN * FOUT;
  const float* sqb = sq + (size_t)z * NN;
  float* Ab = A + (size_t)z * NN * NN;
  const int tr = blockIdx.y * 64, tc = blockIdx.x * 64;
  __shared__ float Ah[64][68];
  __shared__ float Bh[64][68];
  const int tid = threadIdx.x;
  const int tx = tid & 15, ty = tid >> 4;
  for (int s = 0; s < 4; ++s) {
    int slot = tid + (s << 8);
    int r = slot >> 4;
    int c4 = (slot & 15) << 2;
    float4 va = *(const float4*)&hb[(size_t)(tr + r) * FOUT + c4];
    float4 vb = *(const float4*)&hb[(size_t)(tc + r) * FOUT + c4];
    Ah[r][c4] = va.x; Ah[r][c4 + 1] = va.y; Ah[r][c4 + 2] = va.z; Ah[r][c4 + 3] = va.w;
    Bh[r][c4] = vb.x; Bh[r][c4 + 1] = vb.y; Bh[r][c4 + 2] = vb.z; Bh[r][c4 + 3] = vb.w;
  }
  __syncthreads();
  float acc[4][4] = {};
  for (int k = 0; k < 64; ++k) {
    float ra[4], rb[4];
    for (int i = 0; i < 4; ++i) ra[i] = Ah[ty * 4 + i][k];
    for (int j = 0; j < 4; ++j) rb[j] = Bh[tx * 4 + j][k];
    for (int i = 0; i < 4; ++i)
      for (int j = 0; j < 4; ++j) acc[i][j] += ra[i] * rb[j];
  }
  for (int i = 0; i < 4; ++i) {
    int n = tr + ty * 4 + i;
    float sn = sqb[n];
    float vals[4];
    for (int j = 0; j < 4; ++j) {
      int m = tc + tx * 4 + j;
      float d2 = sn + sqb[m] - 2.0f * acc[i][j];
      vals[j] = (n == m) ? 1.0f : ((d2 > 0.0f) ? expf(-sqrtf(d2)) : 1.0f);
    }
    *(float4*)&Ab[(size_t)n * NN + tc + tx * 4] =
        make_float4(vals[0], vals[1], vals[2], vals[3]);
  }
}

// row sums of unnormalized A (all batches)
__global__ void __launch_bounds__(256) k_rowsum(const float* __restrict__ A,
                                                float* __restrict__ rsum) {
  const int bn = blockIdx.x;  // 0..8191
  const float* row = A + (size_t)bn * NN;
  __shared__ float tmp[4];
  const int tid = threadIdx.x;
  float s = 0.f;
  for (int w = 0; w < 4; ++w) s += row[tid + (w << 8)];
  s = blockSumF(s, tmp);
  if (tid == 0) rsum[bn] = fmaxf(s, 1e-12f);
}

// normalize + split hi/lo bf16, normal and transposed layouts
__global__ void __launch_bounds__(256) k_split(const float* __restrict__ A,
                                               const float* __restrict__ rsum,
                                               unsigned short* __restrict__ Ah,
                                               unsigned short* __restrict__ Al,
                                               unsigned short* __restrict__ ATh,
                                               unsigned short* __restrict__ ATl) {
  const int z = blockIdx.z;
  const size_t MAT = (size_t)NN * NN;
  const float* Ab = A + z * MAT;
  const float* rs = rsum + (size_t)z * NN;
  unsigned short* ah = Ah + z * MAT;
  unsigned short* al = Al + z * MAT;
  unsigned short* ath = ATh + z * MAT;
  unsigned short* atl = ATl + z * MAT;
  const int rt = blockIdx.y * 32, ct = blockIdx.x * 32;
  __shared__ unsigned short th[32][33], tl[32][33];
  const int tid = threadIdx.x;
  {
    int r = tid >> 3;
    int c0 = (tid & 7) << 2;
    float4 v = *(const float4*)&Ab[(size_t)(rt + r) * NN + ct + c0];
    float inv = 1.0f / rs[rt + r];
    float vv[4] = {v.x * inv, v.y * inv, v.z * inv, v.w * inv};
    ushort4 h4, l4;
    unsigned short hs[4], ls[4];
    for (int k = 0; k < 4; ++k) {
      hs[k] = f2bu(vv[k]);
      ls[k] = f2bu(vv[k] - bu2f(hs[k]));
      th[r][c0 + k] = hs[k];
      tl[r][c0 + k] = ls[k];
    }
    h4.x = hs[0]; h4.y = hs[1]; h4.z = hs[2]; h4.w = hs[3];
    l4.x = ls[0]; l4.y = ls[1]; l4.z = ls[2]; l4.w = ls[3];
    *(ushort4*)&ah[(size_t)(rt + r) * NN + ct + c0] = h4;
    *(ushort4*)&al[(size_t)(rt + r) * NN + ct + c0] = l4;
  }
  __syncthreads();
  {
    int c = tid >> 3;
    int r0 = (tid & 7) << 2;
    ushort4 h4, l4;
    h4.x = th[r0][c]; h4.y = th[r0 + 1][c]; h4.z = th[r0 + 2][c]; h4.w = th[r0 + 3][c];
    l4.x = tl[r0][c]; l4.y = tl[r0 + 1][c]; l4.z = tl[r0 + 2][c]; l4.w = tl[r0 + 3][c];
    *(ushort4*)&ath[(size_t)(ct + c) * NN + rt + r0] = h4;
    *(ushort4*)&atl[(size_t)(ct + c) * NN + rt + r0] = l4;
  }
}

// MFMA GEMM1: C = A*A (split bf16); writes C transposed hi/lo.
__global__ void __launch_bounds__(256) k_mm1(
    const unsigned short* __restrict__ Ah, const unsigned short* __restrict__ Al,
    const unsigned short* __restrict__ ATh, const unsigned short* __restrict__ ATl,
    unsigned short* __restrict__ CTh, unsigned short* __restrict__ CTl) {
  const int bid = blockIdx.x;
  const int z = bid & 7;
  const int t6 = bid >> 3;
  const int tr = (t6 >> 3) * 128, tc = (t6 & 7) * 128;
  const size_t MAT = (size_t)NN * NN;
  __shared__ unsigned short sm[32768];
  const int tid = threadIdx.x;
  const int wave = tid >> 6, lane = tid & 63;
  const int wm = (wave >> 1) * 64, wn = (wave & 1) * 64;
  const int q = lane >> 4, ln = lane & 15;
  const int rl = lane >> 3;
  const int gcol = ((lane & 7) ^ rl) << 3;
  const unsigned short* gp0;
  unsigned short* lb;
  if (wave == 0)      { gp0 = Ah  + z * MAT + (size_t)tr * NN; lb = sm; }
  else if (wave == 1) { gp0 = Al  + z * MAT + (size_t)tr * NN; lb = sm + 8192; }
  else if (wave == 2) { gp0 = ATh + z * MAT + (size_t)tc * NN; lb = sm + 16384; }
  else                { gp0 = ATl + z * MAT + (size_t)tc * NN; lb = sm + 24576; }
  f32x4 acc[4][4];
  for (int i = 0; i < 4; ++i)
    for (int j = 0; j < 4; ++j) acc[i][j] = (f32x4){0.f, 0.f, 0.f, 0.f};
  const int swz = (ln & 7);
  for (int kc = 0; kc < NN; kc += 64) {
    __syncthreads();
    const unsigned short* gpk = gp0 + kc + gcol;
    for (int t = 0; t < 16; ++t)
      gload_lds16(gpk + (size_t)(t * 8 + rl) * NN, lb + t * 512);
    __syncthreads();
    for (int ks = 0; ks < 2; ++ks) {
      const int gq = ((ks * 4 + q) ^ swz) << 3;
      bf16x8 fah[4], fal[4], fbh[4], fbl[4];
      for (int i = 0; i < 4; ++i) {
        int off = (wm + i * 16 + ln) * 64 + gq;
        fah[i] = *(const bf16x8*)&sm[off];
        fal[i] = *(const bf16x8*)&sm[8192 + off];
      }
      for (int j = 0; j < 4; ++j) {
        int off = (wn + j * 16 + ln) * 64 + gq;
        fbh[j] = *(const bf16x8*)&sm[16384 + off];
        fbl[j] = *(const bf16x8*)&sm[24576 + off];
      }
      for (int i = 0; i < 4; ++i)
        for (int j = 0; j < 4; ++j) {
          acc[i][j] = __builtin_amdgcn_mfma_f32_16x16x32_bf16(fah[i], fbh[j], acc[i][j], 0, 0, 0);
          acc[i][j] = __builtin_amdgcn_mfma_f32_16x16x32_bf16(fah[i], fbl[j], acc[i][j], 0, 0, 0);
          acc[i][j] = __builtin_amdgcn_mfma_f32_16x16x32_bf16(fal[i], fbh[j], acc[i][j], 0, 0, 0);
        }
    }
  }
  unsigned short* cth = CTh + z * MAT;
  unsigned short* ctl = CTl + z * MAT;
  for (int i = 0; i < 4; ++i) {
    int m0 = tr + wm + i * 16 + q * 4;
    for (int j = 0; j < 4; ++j) {
      int n = tc + wn + j * 16 + ln;
      ushort4 h4, l4;
      unsigned short hs[4], ls[4];
      for (int reg = 0; reg < 4; ++reg) {
        float v = acc[i][j][reg];
        hs[reg] = f2bu(v);
        ls[reg] = f2bu(v - bu2f(hs[reg]));
      }
      h4.x = hs[0]; h4.y = hs[1]; h4.z = hs[2]; h4.w = hs[3];
      l4.x = ls[0]; l4.y = ls[1]; l4.z = ls[2]; l4.w = ls[3];
      *(ushort4*)&cth[(size_t)n * NN + m0] = h4;
      *(ushort4*)&ctl[(size_t)n * NN + m0] = l4;
    }
  }
}

// MFMA GEMM2: PT = (A*C)^T (f32), coalesced via LDS-transposed epilogue
__global__ void __launch_bounds__(256) k_mm2(
    const unsigned short* __restrict__ Ah, const unsigned short* __restrict__ Al,
    const unsigned short* __restrict__ CTh, const unsigned short* __restrict__ CTl,
    float* __restrict__ PT) {
  const int bid = blockIdx.x;
  const int z = bid & 7;
  const int t6 = bid >> 3;
  const int tr = (t6 >> 3) * 128, tc = (t6 & 7) * 128;
  const size_t MAT = (size_t)NN * NN;
  __shared__ float smf[128 * 132];  // 67.6 KB; staging aliases first 64 KB
  unsigned short* sm = (unsigned short*)smf;
  const int tid = threadIdx.x;
  const int wave = tid >> 6, lane = tid & 63;
  const int wm = (wave >> 1) * 64, wn = (wave & 1) * 64;
  const int q = lane >> 4, ln = lane & 15;
  const int rl = lane >> 3;
  const int gcol = ((lane & 7) ^ rl) << 3;
  const unsigned short* gp0;
  unsigned short* lb;
  if (wave == 0)      { gp0 = Ah  + z * MAT + (size_t)tr * NN; lb = sm; }
  else if (wave == 1) { gp0 = Al  + z * MAT + (size_t)tr * NN; lb = sm + 8192; }
  else if (wave == 2) { gp0 = CTh + z * MAT + (size_t)tc * NN; lb = sm + 16384; }
  else                { gp0 = CTl + z * MAT + (size_t)tc * NN; lb = sm + 24576; }
  f32x4 acc[4][4];
  for (int i = 0; i < 4; ++i)
    for (int j = 0; j < 4; ++j) acc[i][j] = (f32x4){0.f, 0.f, 0.f, 0.f};
  const int swz = (ln & 7);
  for (int kc = 0; kc < NN; kc += 64) {
    __syncthreads();
    const unsigned short* gpk = gp0 + kc + gcol;
    for (int t = 0; t < 16; ++t)
      gload_lds16(gpk + (size_t)(t * 8 + rl) * NN, lb + t * 512);
    __syncthreads();
    for (int ks = 0; ks < 2; ++ks) {
      const int gq = ((ks * 4 + q) ^ swz) << 3;
      bf16x8 fah[4], fal[4], fbh[4], fbl[4];
      for (int i = 0; i < 4; ++i) {
        int off = (wm + i * 16 + ln) * 64 + gq;
        fah[i] = *(const bf16x8*)&sm[off];
        fal[i] = *(const bf16x8*)&sm[8192 + off];
      }
      for (int j = 0; j < 4; ++j) {
        int off = (wn + j * 16 + ln) * 64 + gq;
        fbh[j] = *(const bf16x8*)&sm[16384 + off];
        fbl[j] = *(const bf16x8*)&sm[24576 + off];
      }
      for (int i = 0; i < 4; ++i)
        for (int j = 0; j < 4; ++j) {
          acc[i][j] = __builtin_amdgcn_mfma_f32_16x16x32_bf16(fah[i], fbh[j], acc[i][j], 0, 0, 0);
          acc[i][j] = __builtin_amdgcn_mfma_f32_16x16x32_bf16(fah[i], fbl[j], acc[i][j], 0, 0, 0);
          acc[i][j] = __builtin_amdgcn_mfma_f32_16x16x32_bf16(fal[i], fbh[j], acc[i][j], 0, 0, 0);
        }
    }
  }
  // epilogue: stage transposed tile (smf[n_local][m_local]) then coalesced rows
  __syncthreads();
  for (int i = 0; i < 4; ++i) {
    int m0 = wm + i * 16 + q * 4;
    for (int j = 0; j < 4; ++j) {
      int n = wn + j * 16 + ln;
      for (int reg = 0; reg < 4; ++reg)
        smf[n * 132 + m0 + reg] = acc[i][j][reg];
    }
  }
  __syncthreads();
  float* ptb = PT + z * MAT;
  {
    int n0 = tid >> 1;              // 0..127
    int ms = (tid & 1) * 64;        // 0 or 64
    for (int k = 0; k < 64; k += 4) {
      float4 w = *(float4*)&smf[n0 * 132 + ms + k];
      *(float4*)&ptb[(size_t)(tc + n0) * NN + tr + ms + k] = w;
    }
  }
}

// combine + symmetrize + threshold accumulators, 64x64 pair tiles.
// On entry S holds PT = P3^T; on exit S = 0.5*(T+T^T), T = A + 0.8C + 0.64P3.
__global__ void __launch_bounds__(256) k_sym2(
    const unsigned short* __restrict__ Ahp, const unsigned short* __restrict__ Alp,
    const unsigned short* __restrict__ AThp, const unsigned short* __restrict__ ATlp,
    const unsigned short* __restrict__ CThp, const unsigned short* __restrict__ CTlp,
    float* __restrict__ S, int* __restrict__ thrmin,
    float* __restrict__ thrsum) {
  const int z = blockIdx.y;
  const size_t base = (size_t)z * NN * NN;
  int p = blockIdx.x;  // 0..135 over 16x16 tile grid, ti<=tj
  int ti = 0, rem = p;
  while (rem >= 16 - ti) {
    rem -= 16 - ti;
    ++ti;
  }
  const int tj = ti + rem;
  const int tid = threadIdx.x;
  const int r = tid >> 2;           // 0..63
  const int c0 = (tid & 3) << 4;    // 0,16,32,48
  __shared__ float Ft[64][65];      // CT[i2] combined -> C(m,n) via [c][r]
  __shared__ float Dt[64][65];      // PT[i2]          -> P3(m,n) via [c][r]
  // stage i2 tile (rows tj*64+r, cols ti*64+c), coalesced
  {
    size_t rowb = base + (size_t)(tj * 64 + r) * NN + ti * 64;
    for (int k = 0; k < 16; k += 4) {
      int c = c0 + k;
      float4 pv = *(const float4*)&S[rowb + c];
      Dt[r][c] = pv.x; Dt[r][c + 1] = pv.y; Dt[r][c + 2] = pv.z; Dt[r][c + 3] = pv.w;
      ushort4 chv = *(const ushort4*)&CThp[rowb + c];
      ushort4 clv = *(const ushort4*)&CTlp[rowb + c];
      Ft[r][c]     = bu2f(chv.x) + bu2f(clv.x);
      Ft[r][c + 1] = bu2f(chv.y) + bu2f(clv.y);
      Ft[r][c + 2] = bu2f(chv.z) + bu2f(clv.z);
      Ft[r][c + 3] = bu2f(chv.w) + bu2f(clv.w);
    }
  }
  __syncthreads();
  // compute v for i1 tile at [r][c0..c0+15]
  float vbuf[16];
  {
    size_t rowb = base + (size_t)(ti * 64 + r) * NN + tj * 64;
    for (int k4 = 0; k4 < 16; k4 += 4) {
      int c = c0 + k4;
      float4 pt1 = *(const float4*)&S[rowb + c];          // P3(n,m)
      ushort4 ah4 = *(const ushort4*)&Ahp[rowb + c];
      ushort4 al4 = *(const ushort4*)&Alp[rowb + c];
      ushort4 th4 = *(const ushort4*)&AThp[rowb + c];
      ushort4 tl4 = *(const ushort4*)&ATlp[rowb + c];
      ushort4 ch4 = *(const ushort4*)&CThp[rowb + c];
      ushort4 cl4 = *(const ushort4*)&CTlp[rowb + c];
      float a_[4] = {bu2f(ah4.x) + bu2f(al4.x), bu2f(ah4.y) + bu2f(al4.y),
                     bu2f(ah4.z) + bu2f(al4.z), bu2f(ah4.w) + bu2f(al4.w)};
      float at[4] = {bu2f(th4.x) + bu2f(tl4.x), bu2f(th4.y) + bu2f(tl4.y),
                     bu2f(th4.z) + bu2f(tl4.z), bu2f(th4.w) + bu2f(tl4.w)};
      float ct[4] = {bu2f(ch4.x) + bu2f(cl4.x), bu2f(ch4.y) + bu2f(cl4.y),
                     bu2f(ch4.z) + bu2f(cl4.z), bu2f(ch4.w) + bu2f(cl4.w)};
      float pt[4] = {pt1.x, pt1.y, pt1.z, pt1.w};
      for (int u = 0; u < 4; ++u) {
        int cc = c + u;
        float v = 0.5f * (a_[u] + at[u]) + 0.4f * (ct[u] + Ft[cc][r]) +
                  0.32f * (pt[u] + Dt[cc][r]);
        vbuf[k4 + u] = v;
        // threshold accumulators (diag positive -> int-min trick ok)
        if (ti == tj) {
          if (r == cc) {
            int n = ti * 64 + r;
            atomicMin(&thrmin[z], __float_as_int(v));
            if (n != 1023) atomicAdd(&thrsum[z], v);
          } else if (cc == r + 1) {
            atomicAdd(&thrsum[z], -v);
          }
        } else if (tj == ti + 1 && r == 63 && cc == 0) {
          atomicAdd(&thrsum[z], -v);  // boundary offdiag
        }
      }
    }
  }
  // write S[i1] rows (coalesced)
  {
    size_t rowb = base + (size_t)(ti * 64 + r) * NN + tj * 64;
    for (int k4 = 0; k4 < 16; k4 += 4)
      *(float4*)&S[rowb + c0 + k4] =
          make_float4(vbuf[k4], vbuf[k4 + 1], vbuf[k4 + 2], vbuf[k4 + 3]);
  }
  // stage v into Dt (reused) for transposed write of S[i2]
  __syncthreads();  // all Dt/Ft reads done
  for (int k = 0; k < 16; ++k) Dt[r][c0 + k] = vbuf[k];
  __syncthreads();
  {
    size_t rowb = base + (size_t)(tj * 64 + r) * NN + ti * 64;
    for (int k4 = 0; k4 < 16; k4 += 4) {
      int c = c0 + k4;
      *(float4*)&S[rowb + c] = make_float4(Dt[c][r], Dt[c + 1][r],
                                           Dt[c + 2][r], Dt[c + 3][r]);
    }
  }
}

__global__ void __launch_bounds__(256) k_stats(const float* __restrict__ S,
                                               const int* __restrict__ thrmin,
                                               const float* __restrict__ thrsum,
                                               const float* __restrict__ wh1,
                                               const float* __restrict__ wh2,
                                               float* __restrict__ meanv,
                                               float* __restrict__ rstdv) {
  const int n = blockIdx.x;
  const int tid = threadIdx.x;
  double s1 = 0.0, s2 = 0.0;
  for (int b = 0; b < BB; ++b) {
    float t = __int_as_float(thrmin[b]) - thrsum[b] / 1023.0f;
    float w1 = wh1[b * NN + n];
    const float* Srow = S + ((size_t)b * NN + n) * NN;
    const float* w2p = wh2 + b * NN;
    for (int m = tid; m < NN; m += 256) {
      float e = w1 + w2p[m];
      e = (e > 0.f) ? e : 0.01f * e;
      float att = (Srow[m] > t) ? e : NEGV;
      s1 += (double)att;
      s2 += (double)att * (double)att;
    }
  }
  __shared__ double red[256];
  red[tid] = s1;
  __syncthreads();
  for (int s = 128; s > 0; s >>= 1) {
    if (tid < s) red[tid] += red[tid + s];
    __syncthreads();
  }
  double t1 = red[0];
  __syncthreads();
  red[tid] = s2;
  __syncthreads();
  for (int s = 128; s > 0; s >>= 1) {
    if (tid < s) red[tid] += red[tid + s];
    __syncthreads();
  }
  double t2 = red[0];
  if (tid == 0) {
    double mean = t1 / 8192.0;
    double var = t2 / 8192.0 - mean * mean;
    if (var < 0.0) var = 0.0;
    meanv[n] = (float)mean;
    rstdv[n] = (float)(1.0 / sqrt(var + 1e-5));
  }
}

__global__ void __launch_bounds__(256) k_out(const float* __restrict__ S,
                                             const int* __restrict__ thrmin,
                                             const float* __restrict__ thrsum,
                                             const float* __restrict__ wh1,
                                             const float* __restrict__ wh2,
                                             const float* __restrict__ meanv,
                                             const float* __restrict__ rstdv,
                                             const float* __restrict__ flag,
                                             void* outv) {
  const int bn = blockIdx.x;
  const int b = bn >> 10;
  const int n = bn & 1023;
  const int tid = threadIdx.x;
  const bool f32m = (flag[0] != 0.0f);
  const float t = __int_as_float(thrmin[b]) - thrsum[b] / 1023.0f;
  const float w1 = wh1[bn];
  const float* Srow = S + (size_t)bn * NN;
  const float* w2p = wh2 + b * NN;
  float v[4];
  float mx = -3.0e38f;
  for (int w = 0; w < 4; ++w) {
    int m = tid + (w << 8);
    float e = w1 + w2p[m];
    e = (e > 0.f) ? e : 0.01f * e;
    float att = (Srow[m] > t) ? e : NEGV;
    float vv = (att - meanv[n]) * rstdv[n];
    v[w] = vv;
    mx = fmaxf(mx, vv);
  }
  __shared__ float tmp[4];
  float gmx = blockMaxF(mx, tmp);
  float sum = 0.f;
  for (int w = 0; w < 4; ++w) {
    v[w] = __expf(v[w] - gmx);
    sum += v[w];
  }
  float gsum = blockSumF(sum, tmp);
  for (int w = 0; w < 4; ++w) {
    int m = tid + (w << 8);
    float val = v[w] / gsum;
    if (f32m) {
      ((float*)outv)[(size_t)bn * NN + m] = val;
    } else {
      ((bf16*)outv)[(size_t)bn * NN + m] = __float2bfloat16(val);
    }
  }
}

extern "C" void kernel_launch(void* const* d_in, const int* in_sizes, int n_in,
                              void* d_out, int out_size, void* d_ws,
                              size_t ws_size, hipStream_t stream) {
  float* ws = (float*)d_ws;

  float* sq = ws;                   // 8192
  float* wh1 = ws + 8192;           // 8192
  float* wh2 = ws + 16384;          // 8192
  float* thrsum = ws + 24576;       // 8
  int* thrmin = (int*)(ws + 24592); // 8
  float* meanv = ws + 24608;        // 1024
  float* rstdv = ws + 25632;        // 1024
  float* flag = ws + 26656;         // 8
  float* rsum = ws + 26664;         // 8192
  float* h = ws + 65536;            // 524288

  unsigned short* Ah = (unsigned short*)(ws + 589824);
  unsigned short* Al = (unsigned short*)(ws + 4784128);
  unsigned short* ATh = (unsigned short*)(ws + 8978432);
  unsigned short* ATl = (unsigned short*)(ws + 13172736);
  unsigned short* CTh = (unsigned short*)(ws + 17367040);
  unsigned short* CTl = (unsigned short*)(ws + 21561344);
  float* Sf = ws + 25755648;  // 8388608 floats (A_un -> PT -> S)
  const size_t needed_fast = (25755648ull + 8388608ull) * 4ull;

  if (ws_size < needed_fast) {
    k_fill<<<dim3(2048), 256, 0, stream>>>((unsigned short*)d_out, out_size,
                                           (unsigned short)0xBF80);
    return;
  }

  k_detect<<<dim3(1), 256, 0, stream>>>((const unsigned short*)d_in[0], flag,
                                        thrmin, thrsum);
  k_h<<<dim3(BB * NN), 64, 0, stream>>>(d_in[0], d_in[1], d_in[2], flag, h, sq,
                                        wh1, wh2);
  k_g<<<dim3(16, 16, BB), 256, 0, stream>>>(h, sq, Sf);
  k_rowsum<<<dim3(BB * NN), 256, 0, stream>>>(Sf, rsum);
  k_split<<<dim3(32, 32, BB), 256, 0, stream>>>(Sf, rsum, Ah, Al, ATh, ATl);
  k_mm1<<<dim3(512), 256, 0, stream>>>(Ah, Al, ATh, ATl, CTh, CTl);
  k_mm2<<<dim3(512), 256, 0, stream>>>(Ah, Al, CTh, CTl, Sf);
  k_sym2<<<dim3(136, BB), 256, 0, stream>>>(Ah, Al, ATh, ATl, CTh, CTl, Sf,
                                            thrmin, thrsum);
  k_stats<<<dim3(NN), 256, 0, stream>>>(Sf, thrmin, thrsum, wh1, wh2, meanv,
                                        rstdv);
  k_out<<<dim3(BB * NN), 256, 0, stream>>>(Sf, thrmin, thrsum, wh1, wh2, meanv,
                                           rstdv, flag, d_out);
}

// Round 9
// 377.347 us; speedup vs baseline: 1.0375x; 1.0375x over previous
//
#include <hip/hip_runtime.h>
#include <hip/hip_bf16.h>

#define BB 8
#define NN 1024
#define FIN 256
#define FOUT 64
#define NEGV (-9000000000000000.0f)

typedef __hip_bfloat16 bf16;
typedef short bf16x8 __attribute__((ext_vector_type(8)));
typedef float f32x4 __attribute__((ext_vector_type(4)));

__device__ __forceinline__ float b2f(bf16 v) { return __bfloat162float(v); }
__device__ __forceinline__ float bu2f(unsigned short u) {
  union { unsigned int i; float f; } c;
  c.i = ((unsigned int)u) << 16;
  return c.f;
}
__device__ __forceinline__ unsigned short f2bu(float v) {
  bf16 t = __float2bfloat16(v);
  return *(unsigned short*)&t;
}

// async global->LDS, 16B per lane; LDS dest is wave-uniform base (+lane*16 by HW)
__device__ __forceinline__ void gload_lds16(const unsigned short* g,
                                            unsigned short* l) {
  __builtin_amdgcn_global_load_lds(
      (__attribute__((address_space(1))) void*)(unsigned long long)(const void*)g,
      (__attribute__((address_space(3))) void*)l, 16, 0, 0);
}

__device__ __forceinline__ float waveRedSum(float v) {
  for (int d = 32; d; d >>= 1) v += __shfl_down(v, d);
  return v;
}
__device__ __forceinline__ float waveRedMax(float v) {
  for (int d = 32; d; d >>= 1) v = fmaxf(v, __shfl_down(v, d));
  return v;
}

__device__ __forceinline__ float blockSumF(float v, float* tmp) {
  __syncthreads();
  v = waveRedSum(v);
  if ((threadIdx.x & 63) == 0) tmp[threadIdx.x >> 6] = v;
  __syncthreads();
  return tmp[0] + tmp[1] + tmp[2] + tmp[3];
}
__device__ __forceinline__ float blockMaxF(float v, float* tmp) {
  __syncthreads();
  v = waveRedMax(v);
  if ((threadIdx.x & 63) == 0) tmp[threadIdx.x >> 6] = v;
  __syncthreads();
  return fmaxf(fmaxf(tmp[0], tmp[1]), fmaxf(tmp[2], tmp[3]));
}

__global__ void k_fill(unsigned short* o, int n, unsigned short pat) {
  int i = blockIdx.x * blockDim.x + threadIdx.x;
  int stride = gridDim.x * blockDim.x;
  for (; i < n; i += stride) o[i] = pat;
}

// dtype probe + init threshold accumulators
__global__ void k_detect(const unsigned short* xu, float* flag,
                         int* thrmin, float* thrsum) {
  const int tid = threadIdx.x;
  if (tid < BB) {
    thrmin[tid] = 0x7F800000;  // +inf (diags are positive)
    thrsum[tid] = 0.f;
  }
  float mx = 0.0f, zc = 0.0f;
  for (int i = tid; i < 8192; i += 256) {
    unsigned short u = xu[i];
    float v = bu2f(u);
    if (u == 0 || u == 0x8000) zc += 1.0f;
    mx = fmaxf(mx, fabsf(v));
  }
  __shared__ float tmp[4];
  float gm = blockMaxF(mx, tmp);
  float gz = blockSumF(zc, tmp);
  if (tid == 0) flag[0] = (gm > 1.0e6f || gz > 2048.0f) ? 1.0f : 0.0f;
}

// h = x @ W per (b,n) row; sq = |h|^2; wh1 = h.a1; wh2 = h.a2
__global__ void __launch_bounds__(64) k_h(const void* xv, const void* Wv,
                                          const void* av,
                                          const float* __restrict__ flag,
                                          float* __restrict__ h,
                                          float* __restrict__ sq,
                                          float* __restrict__ wh1,
                                          float* __restrict__ wh2) {
  const int bn = blockIdx.x;
  const int o = threadIdx.x;
  const bool f32m = (flag[0] != 0.0f);
  __shared__ float xs[FIN];
  if (f32m) {
    const float* xr = (const float*)xv + (size_t)bn * FIN;
    for (int i = o; i < FIN; i += 64) xs[i] = xr[i];
  } else {
    const bf16* xr = (const bf16*)xv + (size_t)bn * FIN;
    for (int i = o; i < FIN; i += 64) xs[i] = b2f(xr[i]);
  }
  __syncthreads();
  float acc = 0.f;
  if (f32m) {
    const float* Wf = (const float*)Wv;
    for (int i = 0; i < FIN; ++i) acc += xs[i] * Wf[i * FOUT + o];
  } else {
    const bf16* Wb = (const bf16*)Wv;
    for (int i = 0; i < FIN; ++i) acc += xs[i] * b2f(Wb[i * FOUT + o]);
  }
  h[(size_t)bn * FOUT + o] = acc;
  float a1, a2;
  if (f32m) {
    a1 = ((const float*)av)[o];
    a2 = ((const float*)av)[FOUT + o];
  } else {
    a1 = b2f(((const bf16*)av)[o]);
    a2 = b2f(((const bf16*)av)[FOUT + o]);
  }
  float s = waveRedSum(acc * acc);
  float w1 = waveRedSum(acc * a1);
  float w2 = waveRedSum(acc * a2);
  if (o == 0) {
    sq[bn] = s;
    wh1[bn] = w1;
    wh2[bn] = w2;
  }
}

// batched: A_un[z][n][m] = exp(-dist), exact 1.0 diag (round-5 proven body)
__global__ void __launch_bounds__(256) k_g(const float* __restrict__ h,
                                           const float* __restrict__ sq,
                                           float* __restrict__ A) {
  const int z = blockIdx.z;
  const float* hb = h + (size_t)z * NN * FOUT;
  const float* sqb = sq + (size_t)z * NN;
  float* Ab = A + (size_t)z * NN * NN;
  const int tr = blockIdx.y * 64, tc = blockIdx.x * 64;
  __shared__ float Ah[64][68];
  __shared__ float Bh[64][68];
  const int tid = threadIdx.x;
  const int tx = tid & 15, ty = tid >> 4;
  for (int s = 0; s < 4; ++s) {
    int slot = tid + (s << 8);
    int r = slot >> 4;
    int c4 = (slot & 15) << 2;
    float4 va = *(const float4*)&hb[(size_t)(tr + r) * FOUT + c4];
    float4 vb = *(const float4*)&hb[(size_t)(tc + r) * FOUT + c4];
    Ah[r][c4] = va.x; Ah[r][c4 + 1] = va.y; Ah[r][c4 + 2] = va.z; Ah[r][c4 + 3] = va.w;
    Bh[r][c4] = vb.x; Bh[r][c4 + 1] = vb.y; Bh[r][c4 + 2] = vb.z; Bh[r][c4 + 3] = vb.w;
  }
  __syncthreads();
  float acc[4][4] = {};
  for (int k = 0; k < 64; ++k) {
    float ra[4], rb[4];
    for (int i = 0; i < 4; ++i) ra[i] = Ah[ty * 4 + i][k];
    for (int j = 0; j < 4; ++j) rb[j] = Bh[tx * 4 + j][k];
    for (int i = 0; i < 4; ++i)
      for (int j = 0; j < 4; ++j) acc[i][j] += ra[i] * rb[j];
  }
  for (int i = 0; i < 4; ++i) {
    int n = tr + ty * 4 + i;
    float sn = sqb[n];
    float vals[4];
    for (int j = 0; j < 4; ++j) {
      int m = tc + tx * 4 + j;
      float d2 = sn + sqb[m] - 2.0f * acc[i][j];
      vals[j] = (n == m) ? 1.0f : ((d2 > 0.0f) ? expf(-sqrtf(d2)) : 1.0f);
    }
    *(float4*)&Ab[(size_t)n * NN + tc + tx * 4] =
        make_float4(vals[0], vals[1], vals[2], vals[3]);
  }
}

// row sums of unnormalized A (all batches)
__global__ void __launch_bounds__(256) k_rowsum(const float* __restrict__ A,
                                                float* __restrict__ rsum) {
  const int bn = blockIdx.x;  // 0..8191
  const float* row = A + (size_t)bn * NN;
  __shared__ float tmp[4];
  const int tid = threadIdx.x;
  float s = 0.f;
  for (int w = 0; w < 4; ++w) s += row[tid + (w << 8)];
  s = blockSumF(s, tmp);
  if (tid == 0) rsum[bn] = fmaxf(s, 1e-12f);
}

// normalize + split hi/lo bf16, normal and transposed layouts
__global__ void __launch_bounds__(256) k_split(const float* __restrict__ A,
                                               const float* __restrict__ rsum,
                                               unsigned short* __restrict__ Ah,
                                               unsigned short* __restrict__ Al,
                                               unsigned short* __restrict__ ATh,
                                               unsigned short* __restrict__ ATl) {
  const int z = blockIdx.z;
  const size_t MAT = (size_t)NN * NN;
  const float* Ab = A + z * MAT;
  const float* rs = rsum + (size_t)z * NN;
  unsigned short* ah = Ah + z * MAT;
  unsigned short* al = Al + z * MAT;
  unsigned short* ath = ATh + z * MAT;
  unsigned short* atl = ATl + z * MAT;
  const int rt = blockIdx.y * 32, ct = blockIdx.x * 32;
  __shared__ unsigned short th[32][33], tl[32][33];
  const int tid = threadIdx.x;
  {
    int r = tid >> 3;
    int c0 = (tid & 7) << 2;
    float4 v = *(const float4*)&Ab[(size_t)(rt + r) * NN + ct + c0];
    float inv = 1.0f / rs[rt + r];
    float vv[4] = {v.x * inv, v.y * inv, v.z * inv, v.w * inv};
    ushort4 h4, l4;
    unsigned short hs[4], ls[4];
    for (int k = 0; k < 4; ++k) {
      hs[k] = f2bu(vv[k]);
      ls[k] = f2bu(vv[k] - bu2f(hs[k]));
      th[r][c0 + k] = hs[k];
      tl[r][c0 + k] = ls[k];
    }
    h4.x = hs[0]; h4.y = hs[1]; h4.z = hs[2]; h4.w = hs[3];
    l4.x = ls[0]; l4.y = ls[1]; l4.z = ls[2]; l4.w = ls[3];
    *(ushort4*)&ah[(size_t)(rt + r) * NN + ct + c0] = h4;
    *(ushort4*)&al[(size_t)(rt + r) * NN + ct + c0] = l4;
  }
  __syncthreads();
  {
    int c = tid >> 3;
    int r0 = (tid & 7) << 2;
    ushort4 h4, l4;
    h4.x = th[r0][c]; h4.y = th[r0 + 1][c]; h4.z = th[r0 + 2][c]; h4.w = th[r0 + 3][c];
    l4.x = tl[r0][c]; l4.y = tl[r0 + 1][c]; l4.z = tl[r0 + 2][c]; l4.w = tl[r0 + 3][c];
    *(ushort4*)&ath[(size_t)(ct + c) * NN + rt + r0] = h4;
    *(ushort4*)&atl[(size_t)(ct + c) * NN + rt + r0] = l4;
  }
}

// MFMA GEMM1: C = A*A (split bf16); writes C transposed hi/lo.
__global__ void __launch_bounds__(256) k_mm1(
    const unsigned short* __restrict__ Ah, const unsigned short* __restrict__ Al,
    const unsigned short* __restrict__ ATh, const unsigned short* __restrict__ ATl,
    unsigned short* __restrict__ CTh, unsigned short* __restrict__ CTl) {
  const int bid = blockIdx.x;
  const int z = bid & 7;
  const int t6 = bid >> 3;
  const int tr = (t6 >> 3) * 128, tc = (t6 & 7) * 128;
  const size_t MAT = (size_t)NN * NN;
  __shared__ unsigned short sm[32768];
  const int tid = threadIdx.x;
  const int wave = tid >> 6, lane = tid & 63;
  const int wm = (wave >> 1) * 64, wn = (wave & 1) * 64;
  const int q = lane >> 4, ln = lane & 15;
  const int rl = lane >> 3;
  const int gcol = ((lane & 7) ^ rl) << 3;
  const unsigned short* gp0;
  unsigned short* lb;
  if (wave == 0)      { gp0 = Ah  + z * MAT + (size_t)tr * NN; lb = sm; }
  else if (wave == 1) { gp0 = Al  + z * MAT + (size_t)tr * NN; lb = sm + 8192; }
  else if (wave == 2) { gp0 = ATh + z * MAT + (size_t)tc * NN; lb = sm + 16384; }
  else                { gp0 = ATl + z * MAT + (size_t)tc * NN; lb = sm + 24576; }
  f32x4 acc[4][4];
  for (int i = 0; i < 4; ++i)
    for (int j = 0; j < 4; ++j) acc[i][j] = (f32x4){0.f, 0.f, 0.f, 0.f};
  const int swz = (ln & 7);
  for (int kc = 0; kc < NN; kc += 64) {
    __syncthreads();
    const unsigned short* gpk = gp0 + kc + gcol;
    for (int t = 0; t < 16; ++t)
      gload_lds16(gpk + (size_t)(t * 8 + rl) * NN, lb + t * 512);
    __syncthreads();
    for (int ks = 0; ks < 2; ++ks) {
      const int gq = ((ks * 4 + q) ^ swz) << 3;
      bf16x8 fah[4], fal[4], fbh[4], fbl[4];
      for (int i = 0; i < 4; ++i) {
        int off = (wm + i * 16 + ln) * 64 + gq;
        fah[i] = *(const bf16x8*)&sm[off];
        fal[i] = *(const bf16x8*)&sm[8192 + off];
      }
      for (int j = 0; j < 4; ++j) {
        int off = (wn + j * 16 + ln) * 64 + gq;
        fbh[j] = *(const bf16x8*)&sm[16384 + off];
        fbl[j] = *(const bf16x8*)&sm[24576 + off];
      }
      for (int i = 0; i < 4; ++i)
        for (int j = 0; j < 4; ++j) {
          acc[i][j] = __builtin_amdgcn_mfma_f32_16x16x32_bf16(fah[i], fbh[j], acc[i][j], 0, 0, 0);
          acc[i][j] = __builtin_amdgcn_mfma_f32_16x16x32_bf16(fah[i], fbl[j], acc[i][j], 0, 0, 0);
          acc[i][j] = __builtin_amdgcn_mfma_f32_16x16x32_bf16(fal[i], fbh[j], acc[i][j], 0, 0, 0);
        }
    }
  }
  unsigned short* cth = CTh + z * MAT;
  unsigned short* ctl = CTl + z * MAT;
  for (int i = 0; i < 4; ++i) {
    int m0 = tr + wm + i * 16 + q * 4;
    for (int j = 0; j < 4; ++j) {
      int n = tc + wn + j * 16 + ln;
      ushort4 h4, l4;
      unsigned short hs[4], ls[4];
      for (int reg = 0; reg < 4; ++reg) {
        float v = acc[i][j][reg];
        hs[reg] = f2bu(v);
        ls[reg] = f2bu(v - bu2f(hs[reg]));
      }
      h4.x = hs[0]; h4.y = hs[1]; h4.z = hs[2]; h4.w = hs[3];
      l4.x = ls[0]; l4.y = ls[1]; l4.z = ls[2]; l4.w = ls[3];
      *(ushort4*)&cth[(size_t)n * NN + m0] = h4;
      *(ushort4*)&ctl[(size_t)n * NN + m0] = l4;
    }
  }
}

// MFMA GEMM2 + fused combine: U = T^T = AT + 0.8*CT + 0.64*(A*C)^T, coalesced.
__global__ void __launch_bounds__(256) k_mm2(
    const unsigned short* __restrict__ Ah, const unsigned short* __restrict__ Al,
    const unsigned short* __restrict__ ATh, const unsigned short* __restrict__ ATl,
    const unsigned short* __restrict__ CTh, const unsigned short* __restrict__ CTl,
    float* __restrict__ U) {
  const int bid = blockIdx.x;
  const int z = bid & 7;
  const int t6 = bid >> 3;
  const int tr = (t6 >> 3) * 128, tc = (t6 & 7) * 128;
  const size_t MAT = (size_t)NN * NN;
  __shared__ float smf[128 * 132];  // 67.6 KB; staging aliases first 64 KB
  unsigned short* sm = (unsigned short*)smf;
  const int tid = threadIdx.x;
  const int wave = tid >> 6, lane = tid & 63;
  const int wm = (wave >> 1) * 64, wn = (wave & 1) * 64;
  const int q = lane >> 4, ln = lane & 15;
  const int rl = lane >> 3;
  const int gcol = ((lane & 7) ^ rl) << 3;
  const unsigned short* gp0;
  unsigned short* lb;
  if (wave == 0)      { gp0 = Ah  + z * MAT + (size_t)tr * NN; lb = sm; }
  else if (wave == 1) { gp0 = Al  + z * MAT + (size_t)tr * NN; lb = sm + 8192; }
  else if (wave == 2) { gp0 = CTh + z * MAT + (size_t)tc * NN; lb = sm + 16384; }
  else                { gp0 = CTl + z * MAT + (size_t)tc * NN; lb = sm + 24576; }
  f32x4 acc[4][4];
  for (int i = 0; i < 4; ++i)
    for (int j = 0; j < 4; ++j) acc[i][j] = (f32x4){0.f, 0.f, 0.f, 0.f};
  const int swz = (ln & 7);
  for (int kc = 0; kc < NN; kc += 64) {
    __syncthreads();
    const unsigned short* gpk = gp0 + kc + gcol;
    for (int t = 0; t < 16; ++t)
      gload_lds16(gpk + (size_t)(t * 8 + rl) * NN, lb + t * 512);
    __syncthreads();
    for (int ks = 0; ks < 2; ++ks) {
      const int gq = ((ks * 4 + q) ^ swz) << 3;
      bf16x8 fah[4], fal[4], fbh[4], fbl[4];
      for (int i = 0; i < 4; ++i) {
        int off = (wm + i * 16 + ln) * 64 + gq;
        fah[i] = *(const bf16x8*)&sm[off];
        fal[i] = *(const bf16x8*)&sm[8192 + off];
      }
      for (int j = 0; j < 4; ++j) {
        int off = (wn + j * 16 + ln) * 64 + gq;
        fbh[j] = *(const bf16x8*)&sm[16384 + off];
        fbl[j] = *(const bf16x8*)&sm[24576 + off];
      }
      for (int i = 0; i < 4; ++i)
        for (int j = 0; j < 4; ++j) {
          acc[i][j] = __builtin_amdgcn_mfma_f32_16x16x32_bf16(fah[i], fbh[j], acc[i][j], 0, 0, 0);
          acc[i][j] = __builtin_amdgcn_mfma_f32_16x16x32_bf16(fah[i], fbl[j], acc[i][j], 0, 0, 0);
          acc[i][j] = __builtin_amdgcn_mfma_f32_16x16x32_bf16(fal[i], fbh[j], acc[i][j], 0, 0, 0);
        }
    }
  }
  // epilogue: stage P3^T tile (smf[n][m]); then U rows = AT + 0.8CT + 0.64P3^T
  __syncthreads();
  for (int i = 0; i < 4; ++i) {
    int m0 = wm + i * 16 + q * 4;
    for (int j = 0; j < 4; ++j) {
      int n = wn + j * 16 + ln;
      for (int reg = 0; reg < 4; ++reg)
        smf[n * 132 + m0 + reg] = acc[i][j][reg];
    }
  }
  __syncthreads();
  {
    const unsigned short* athz = ATh + z * MAT;
    const unsigned short* atlz = ATl + z * MAT;
    const unsigned short* cthz = CTh + z * MAT;
    const unsigned short* ctlz = CTl + z * MAT;
    float* ub = U + z * MAT;
    int n0 = tid >> 1;              // 0..127
    int ms = (tid & 1) * 64;        // 0 or 64
    size_t grow = (size_t)(tc + n0) * NN + tr + ms;
    for (int k = 0; k < 64; k += 4) {
      float4 pv = *(float4*)&smf[n0 * 132 + ms + k];
      ushort4 ah4 = *(const ushort4*)&athz[grow + k];
      ushort4 al4 = *(const ushort4*)&atlz[grow + k];
      ushort4 ch4 = *(const ushort4*)&cthz[grow + k];
      ushort4 cl4 = *(const ushort4*)&ctlz[grow + k];
      float4 w;
      w.x = (bu2f(ah4.x) + bu2f(al4.x)) + 0.8f * (bu2f(ch4.x) + bu2f(cl4.x)) + 0.64f * pv.x;
      w.y = (bu2f(ah4.y) + bu2f(al4.y)) + 0.8f * (bu2f(ch4.y) + bu2f(cl4.y)) + 0.64f * pv.y;
      w.z = (bu2f(ah4.z) + bu2f(al4.z)) + 0.8f * (bu2f(ch4.z) + bu2f(cl4.z)) + 0.64f * pv.z;
      w.w = (bu2f(ah4.w) + bu2f(al4.w)) + 0.8f * (bu2f(ch4.w) + bu2f(cl4.w)) + 0.64f * pv.w;
      *(float4*)&ub[grow + k] = w;
    }
  }
}

// S = (U + U^T)/2 in place, 32x32 pair tiles; fused threshold accumulators.
__global__ void __launch_bounds__(256) k_symf(float* __restrict__ S,
                                              int* __restrict__ thrmin,
                                              float* __restrict__ thrsum) {
  const int z = blockIdx.y;
  float* Sb = S + (size_t)z * NN * NN;
  int p = blockIdx.x;  // 0..527 -> (ti<=tj)
  int ti = 0, rem = p;
  while (rem >= 32 - ti) {
    rem -= 32 - ti;
    ++ti;
  }
  const int tj = ti + rem;
  __shared__ float D1[32][33], D2[32][33];
  const int tid = threadIdx.x;
  for (int s = 0; s < 4; ++s) {
    int slot = tid + (s << 8);
    int r = slot >> 5, c = slot & 31;
    D1[r][c] = Sb[(size_t)(ti * 32 + r) * NN + tj * 32 + c];
    D2[r][c] = Sb[(size_t)(tj * 32 + r) * NN + ti * 32 + c];
  }
  __syncthreads();
  for (int s = 0; s < 4; ++s) {
    int slot = tid + (s << 8);
    int r = slot >> 5, c = slot & 31;
    float v1 = 0.5f * (D1[r][c] + D2[c][r]);
    float v2 = 0.5f * (D2[r][c] + D1[c][r]);
    Sb[(size_t)(ti * 32 + r) * NN + tj * 32 + c] = v1;
    Sb[(size_t)(tj * 32 + r) * NN + ti * 32 + c] = v2;
    // threshold accumulators (diag positive -> int-min trick ok)
    if (ti == tj) {
      if (r == c) {
        int n = ti * 32 + r;
        atomicMin(&thrmin[z], __float_as_int(v1));
        if (n != 1023) atomicAdd(&thrsum[z], v1);
      } else if (c == r + 1) {
        atomicAdd(&thrsum[z], -v1);
      }
    } else if (tj == ti + 1 && r == 31 && c == 0) {
      atomicAdd(&thrsum[z], -v1);  // boundary offdiag (32*tj-1, 32*tj)
    }
  }
}

__global__ void __launch_bounds__(256) k_stats(const float* __restrict__ S,
                                               const int* __restrict__ thrmin,
                                               const float* __restrict__ thrsum,
                                               const float* __restrict__ wh1,
                                               const float* __restrict__ wh2,
                                               float* __restrict__ meanv,
                                               float* __restrict__ rstdv) {
  const int n = blockIdx.x;
  const int tid = threadIdx.x;
  double s1 = 0.0, s2 = 0.0;
  for (int b = 0; b < BB; ++b) {
    float t = __int_as_float(thrmin[b]) - thrsum[b] / 1023.0f;
    float w1 = wh1[b * NN + n];
    const float* Srow = S + ((size_t)b * NN + n) * NN;
    const float* w2p = wh2 + b * NN;
    for (int m = tid; m < NN; m += 256) {
      float e = w1 + w2p[m];
      e = (e > 0.f) ? e : 0.01f * e;
      float att = (Srow[m] > t) ? e : NEGV;
      s1 += (double)att;
      s2 += (double)att * (double)att;
    }
  }
  __shared__ double red[256];
  red[tid] = s1;
  __syncthreads();
  for (int s = 128; s > 0; s >>= 1) {
    if (tid < s) red[tid] += red[tid + s];
    __syncthreads();
  }
  double t1 = red[0];
  __syncthreads();
  red[tid] = s2;
  __syncthreads();
  for (int s = 128; s > 0; s >>= 1) {
    if (tid < s) red[tid] += red[tid + s];
    __syncthreads();
  }
  double t2 = red[0];
  if (tid == 0) {
    double mean = t1 / 8192.0;
    double var = t2 / 8192.0 - mean * mean;
    if (var < 0.0) var = 0.0;
    meanv[n] = (float)mean;
    rstdv[n] = (float)(1.0 / sqrt(var + 1e-5));
  }
}

__global__ void __launch_bounds__(256) k_out(const float* __restrict__ S,
                                             const int* __restrict__ thrmin,
                                             const float* __restrict__ thrsum,
                                             const float* __restrict__ wh1,
                                             const float* __restrict__ wh2,
                                             const float* __restrict__ meanv,
                                             const float* __restrict__ rstdv,
                                             const float* __restrict__ flag,
                                             void* outv) {
  const int bn = blockIdx.x;
  const int b = bn >> 10;
  const int n = bn & 1023;
  const int tid = threadIdx.x;
  const bool f32m = (flag[0] != 0.0f);
  const float t = __int_as_float(thrmin[b]) - thrsum[b] / 1023.0f;
  const float w1 = wh1[bn];
  const float* Srow = S + (size_t)bn * NN;
  const float* w2p = wh2 + b * NN;
  float v[4];
  float mx = -3.0e38f;
  for (int w = 0; w < 4; ++w) {
    int m = tid + (w << 8);
    float e = w1 + w2p[m];
    e = (e > 0.f) ? e : 0.01f * e;
    float att = (Srow[m] > t) ? e : NEGV;
    float vv = (att - meanv[n]) * rstdv[n];
    v[w] = vv;
    mx = fmaxf(mx, vv);
  }
  __shared__ float tmp[4];
  float gmx = blockMaxF(mx, tmp);
  float sum = 0.f;
  for (int w = 0; w < 4; ++w) {
    v[w] = __expf(v[w] - gmx);
    sum += v[w];
  }
  float gsum = blockSumF(sum, tmp);
  for (int w = 0; w < 4; ++w) {
    int m = tid + (w << 8);
    float val = v[w] / gsum;
    if (f32m) {
      ((float*)outv)[(size_t)bn * NN + m] = val;
    } else {
      ((bf16*)outv)[(size_t)bn * NN + m] = __float2bfloat16(val);
    }
  }
}

extern "C" void kernel_launch(void* const* d_in, const int* in_sizes, int n_in,
                              void* d_out, int out_size, void* d_ws,
                              size_t ws_size, hipStream_t stream) {
  float* ws = (float*)d_ws;

  float* sq = ws;                   // 8192
  float* wh1 = ws + 8192;           // 8192
  float* wh2 = ws + 16384;          // 8192
  float* thrsum = ws + 24576;       // 8
  int* thrmin = (int*)(ws + 24592); // 8
  float* meanv = ws + 24608;        // 1024
  float* rstdv = ws + 25632;        // 1024
  float* flag = ws + 26656;         // 8
  float* rsum = ws + 26664;         // 8192
  float* h = ws + 65536;            // 524288

  unsigned short* Ah = (unsigned short*)(ws + 589824);
  unsigned short* Al = (unsigned short*)(ws + 4784128);
  unsigned short* ATh = (unsigned short*)(ws + 8978432);
  unsigned short* ATl = (unsigned short*)(ws + 13172736);
  unsigned short* CTh = (unsigned short*)(ws + 17367040);
  unsigned short* CTl = (unsigned short*)(ws + 21561344);
  float* Sf = ws + 25755648;  // 8388608 floats (A_un -> U -> S)
  const size_t needed_fast = (25755648ull + 8388608ull) * 4ull;

  if (ws_size < needed_fast) {
    k_fill<<<dim3(2048), 256, 0, stream>>>((unsigned short*)d_out, out_size,
                                           (unsigned short)0xBF80);
    return;
  }

  k_detect<<<dim3(1), 256, 0, stream>>>((const unsigned short*)d_in[0], flag,
                                        thrmin, thrsum);
  k_h<<<dim3(BB * NN), 64, 0, stream>>>(d_in[0], d_in[1], d_in[2], flag, h, sq,
                                        wh1, wh2);
  k_g<<<dim3(16, 16, BB), 256, 0, stream>>>(h, sq, Sf);
  k_rowsum<<<dim3(BB * NN), 256, 0, stream>>>(Sf, rsum);
  k_split<<<dim3(32, 32, BB), 256, 0, stream>>>(Sf, rsum, Ah, Al, ATh, ATl);
  k_mm1<<<dim3(512), 256, 0, stream>>>(Ah, Al, ATh, ATl, CTh, CTl);
  k_mm2<<<dim3(512), 256, 0, stream>>>(Ah, Al, ATh, ATl, CTh, CTl, Sf);
  k_symf<<<dim3(528, BB), 256, 0, stream>>>(Sf, thrmin, thrsum);
  k_stats<<<dim3(NN), 256, 0, stream>>>(Sf, thrmin, thrsum, wh1, wh2, meanv,
                                        rstdv);
  k_out<<<dim3(BB * NN), 256, 0, stream>>>(Sf, thrmin, thrsum, wh1, wh2, meanv,
                                           rstdv, flag, d_out);
}

// Round 10
// 288.559 us; speedup vs baseline: 1.3568x; 1.3077x over previous
//
#include <hip/hip_runtime.h>
#include <hip/hip_bf16.h>

#define BB 8
#define NN 1024
#define FIN 256
#define FOUT 64
#define NEGV (-9000000000000000.0f)

typedef __hip_bfloat16 bf16;
typedef short bf16x8 __attribute__((ext_vector_type(8)));
typedef float f32x4 __attribute__((ext_vector_type(4)));

__device__ __forceinline__ float b2f(bf16 v) { return __bfloat162float(v); }
__device__ __forceinline__ float bu2f(unsigned short u) {
  union { unsigned int i; float f; } c;
  c.i = ((unsigned int)u) << 16;
  return c.f;
}
__device__ __forceinline__ unsigned short f2bu(float v) {
  bf16 t = __float2bfloat16(v);
  return *(unsigned short*)&t;
}

// async global->LDS, 16B per lane; LDS dest is wave-uniform base (+lane*16 by HW)
__device__ __forceinline__ void gload_lds16(const unsigned short* g,
                                            unsigned short* l) {
  __builtin_amdgcn_global_load_lds(
      (__attribute__((address_space(1))) void*)(unsigned long long)(const void*)g,
      (__attribute__((address_space(3))) void*)l, 16, 0, 0);
}

__device__ __forceinline__ float waveRedSum(float v) {
  for (int d = 32; d; d >>= 1) v += __shfl_down(v, d);
  return v;
}
__device__ __forceinline__ float waveRedMax(float v) {
  for (int d = 32; d; d >>= 1) v = fmaxf(v, __shfl_down(v, d));
  return v;
}
__device__ __forceinline__ float waveRedMin(float v) {
  for (int d = 32; d; d >>= 1) v = fminf(v, __shfl_down(v, d));
  return v;
}

__device__ __forceinline__ float blockSumF(float v, float* tmp) {
  __syncthreads();
  v = waveRedSum(v);
  if ((threadIdx.x & 63) == 0) tmp[threadIdx.x >> 6] = v;
  __syncthreads();
  return tmp[0] + tmp[1] + tmp[2] + tmp[3];
}
__device__ __forceinline__ float blockMaxF(float v, float* tmp) {
  __syncthreads();
  v = waveRedMax(v);
  if ((threadIdx.x & 63) == 0) tmp[threadIdx.x >> 6] = v;
  __syncthreads();
  return fmaxf(fmaxf(tmp[0], tmp[1]), fmaxf(tmp[2], tmp[3]));
}
__device__ __forceinline__ float blockMinF(float v, float* tmp) {
  __syncthreads();
  v = waveRedMin(v);
  if ((threadIdx.x & 63) == 0) tmp[threadIdx.x >> 6] = v;
  __syncthreads();
  return fminf(fminf(tmp[0], tmp[1]), fminf(tmp[2], tmp[3]));
}

__global__ void k_fill(unsigned short* o, int n, unsigned short pat) {
  int i = blockIdx.x * blockDim.x + threadIdx.x;
  int stride = gridDim.x * blockDim.x;
  for (; i < n; i += stride) o[i] = pat;
}

// dtype probe
__global__ void k_detect(const unsigned short* xu, float* flag) {
  const int tid = threadIdx.x;
  float mx = 0.0f, zc = 0.0f;
  for (int i = tid; i < 8192; i += 256) {
    unsigned short u = xu[i];
    float v = bu2f(u);
    if (u == 0 || u == 0x8000) zc += 1.0f;
    mx = fmaxf(mx, fabsf(v));
  }
  __shared__ float tmp[4];
  float gm = blockMaxF(mx, tmp);
  float gz = blockSumF(zc, tmp);
  if (tid == 0) flag[0] = (gm > 1.0e6f || gz > 2048.0f) ? 1.0f : 0.0f;
}

// h = x @ W per (b,n) row; sq = |h|^2; wh1 = h.a1; wh2 = h.a2
__global__ void __launch_bounds__(64) k_h(const void* xv, const void* Wv,
                                          const void* av,
                                          const float* __restrict__ flag,
                                          float* __restrict__ h,
                                          float* __restrict__ sq,
                                          float* __restrict__ wh1,
                                          float* __restrict__ wh2) {
  const int bn = blockIdx.x;
  const int o = threadIdx.x;
  const bool f32m = (flag[0] != 0.0f);
  __shared__ float xs[FIN];
  if (f32m) {
    const float* xr = (const float*)xv + (size_t)bn * FIN;
    for (int i = o; i < FIN; i += 64) xs[i] = xr[i];
  } else {
    const bf16* xr = (const bf16*)xv + (size_t)bn * FIN;
    for (int i = o; i < FIN; i += 64) xs[i] = b2f(xr[i]);
  }
  __syncthreads();
  float acc = 0.f;
  if (f32m) {
    const float* Wf = (const float*)Wv;
    for (int i = 0; i < FIN; ++i) acc += xs[i] * Wf[i * FOUT + o];
  } else {
    const bf16* Wb = (const bf16*)Wv;
    for (int i = 0; i < FIN; ++i) acc += xs[i] * b2f(Wb[i * FOUT + o]);
  }
  h[(size_t)bn * FOUT + o] = acc;
  float a1, a2;
  if (f32m) {
    a1 = ((const float*)av)[o];
    a2 = ((const float*)av)[FOUT + o];
  } else {
    a1 = b2f(((const bf16*)av)[o]);
    a2 = b2f(((const bf16*)av)[FOUT + o]);
  }
  float s = waveRedSum(acc * acc);
  float w1 = waveRedSum(acc * a1);
  float w2 = waveRedSum(acc * a2);
  if (o == 0) {
    sq[bn] = s;
    wh1[bn] = w1;
    wh2[bn] = w2;
  }
}

// batched: A_un[z][n][m] = exp(-dist), exact 1.0 diag (proven scalar body)
__global__ void __launch_bounds__(256) k_g(const float* __restrict__ h,
                                           const float* __restrict__ sq,
                                           float* __restrict__ A) {
  const int z = blockIdx.z;
  const float* hb = h + (size_t)z * NN * FOUT;
  const float* sqb = sq + (size_t)z * NN;
  float* Ab = A + (size_t)z * NN * NN;
  const int tr = blockIdx.y * 64, tc = blockIdx.x * 64;
  __shared__ float Ah[64][68];
  __shared__ float Bh[64][68];
  const int tid = threadIdx.x;
  const int tx = tid & 15, ty = tid >> 4;
  for (int s = 0; s < 4; ++s) {
    int slot = tid + (s << 8);
    int r = slot >> 4;
    int c4 = (slot & 15) << 2;
    float4 va = *(const float4*)&hb[(size_t)(tr + r) * FOUT + c4];
    float4 vb = *(const float4*)&hb[(size_t)(tc + r) * FOUT + c4];
    Ah[r][c4] = va.x; Ah[r][c4 + 1] = va.y; Ah[r][c4 + 2] = va.z; Ah[r][c4 + 3] = va.w;
    Bh[r][c4] = vb.x; Bh[r][c4 + 1] = vb.y; Bh[r][c4 + 2] = vb.z; Bh[r][c4 + 3] = vb.w;
  }
  __syncthreads();
  float acc[4][4] = {};
  for (int k = 0; k < 64; ++k) {
    float ra[4], rb[4];
    for (int i = 0; i < 4; ++i) ra[i] = Ah[ty * 4 + i][k];
    for (int j = 0; j < 4; ++j) rb[j] = Bh[tx * 4 + j][k];
    for (int i = 0; i < 4; ++i)
      for (int j = 0; j < 4; ++j) acc[i][j] += ra[i] * rb[j];
  }
  for (int i = 0; i < 4; ++i) {
    int n = tr + ty * 4 + i;
    float sn = sqb[n];
    float vals[4];
    for (int j = 0; j < 4; ++j) {
      int m = tc + tx * 4 + j;
      float d2 = sn + sqb[m] - 2.0f * acc[i][j];
      vals[j] = (n == m) ? 1.0f : ((d2 > 0.0f) ? expf(-sqrtf(d2)) : 1.0f);
    }
    *(float4*)&Ab[(size_t)n * NN + tc + tx * 4] =
        make_float4(vals[0], vals[1], vals[2], vals[3]);
  }
}

// row sums of unnormalized A (all batches)
__global__ void __launch_bounds__(256) k_rowsum(const float* __restrict__ A,
                                                float* __restrict__ rsum) {
  const int bn = blockIdx.x;
  const float* row = A + (size_t)bn * NN;
  __shared__ float tmp[4];
  const int tid = threadIdx.x;
  float s = 0.f;
  for (int w = 0; w < 4; ++w) s += row[tid + (w << 8)];
  s = blockSumF(s, tmp);
  if (tid == 0) rsum[bn] = fmaxf(s, 1e-12f);
}

// normalize + split hi/lo bf16, normal and transposed layouts
__global__ void __launch_bounds__(256) k_split(const float* __restrict__ A,
                                               const float* __restrict__ rsum,
                                               unsigned short* __restrict__ Ah,
                                               unsigned short* __restrict__ Al,
                                               unsigned short* __restrict__ ATh,
                                               unsigned short* __restrict__ ATl) {
  const int z = blockIdx.z;
  const size_t MAT = (size_t)NN * NN;
  const float* Ab = A + z * MAT;
  const float* rs = rsum + (size_t)z * NN;
  unsigned short* ah = Ah + z * MAT;
  unsigned short* al = Al + z * MAT;
  unsigned short* ath = ATh + z * MAT;
  unsigned short* atl = ATl + z * MAT;
  const int rt = blockIdx.y * 32, ct = blockIdx.x * 32;
  __shared__ unsigned short th[32][33], tl[32][33];
  const int tid = threadIdx.x;
  {
    int r = tid >> 3;
    int c0 = (tid & 7) << 2;
    float4 v = *(const float4*)&Ab[(size_t)(rt + r) * NN + ct + c0];
    float inv = 1.0f / rs[rt + r];
    float vv[4] = {v.x * inv, v.y * inv, v.z * inv, v.w * inv};
    ushort4 h4, l4;
    unsigned short hs[4], ls[4];
    for (int k = 0; k < 4; ++k) {
      hs[k] = f2bu(vv[k]);
      ls[k] = f2bu(vv[k] - bu2f(hs[k]));
      th[r][c0 + k] = hs[k];
      tl[r][c0 + k] = ls[k];
    }
    h4.x = hs[0]; h4.y = hs[1]; h4.z = hs[2]; h4.w = hs[3];
    l4.x = ls[0]; l4.y = ls[1]; l4.z = ls[2]; l4.w = ls[3];
    *(ushort4*)&ah[(size_t)(rt + r) * NN + ct + c0] = h4;
    *(ushort4*)&al[(size_t)(rt + r) * NN + ct + c0] = l4;
  }
  __syncthreads();
  {
    int c = tid >> 3;
    int r0 = (tid & 7) << 2;
    ushort4 h4, l4;
    h4.x = th[r0][c]; h4.y = th[r0 + 1][c]; h4.z = th[r0 + 2][c]; h4.w = th[r0 + 3][c];
    l4.x = tl[r0][c]; l4.y = tl[r0 + 1][c]; l4.z = tl[r0 + 2][c]; l4.w = tl[r0 + 3][c];
    *(ushort4*)&ath[(size_t)(ct + c) * NN + rt + r0] = h4;
    *(ushort4*)&atl[(size_t)(ct + c) * NN + rt + r0] = l4;
  }
}

// MFMA GEMM1: C = A*A (split bf16); writes C transposed hi/lo. (294-µs proven)
__global__ void __launch_bounds__(256) k_mm1(
    const unsigned short* __restrict__ Ah, const unsigned short* __restrict__ Al,
    const unsigned short* __restrict__ ATh, const unsigned short* __restrict__ ATl,
    unsigned short* __restrict__ CTh, unsigned short* __restrict__ CTl) {
  const int bid = blockIdx.x;
  const int z = bid & 7;
  const int t6 = bid >> 3;
  const int tr = (t6 >> 3) * 128, tc = (t6 & 7) * 128;
  const size_t MAT = (size_t)NN * NN;
  __shared__ unsigned short sm[32768];
  const int tid = threadIdx.x;
  const int wave = tid >> 6, lane = tid & 63;
  const int wm = (wave >> 1) * 64, wn = (wave & 1) * 64;
  const int q = lane >> 4, ln = lane & 15;
  const int rl = lane >> 3;
  const int gcol = ((lane & 7) ^ rl) << 3;
  const unsigned short* gp0;
  unsigned short* lb;
  if (wave == 0)      { gp0 = Ah  + z * MAT + (size_t)tr * NN; lb = sm; }
  else if (wave == 1) { gp0 = Al  + z * MAT + (size_t)tr * NN; lb = sm + 8192; }
  else if (wave == 2) { gp0 = ATh + z * MAT + (size_t)tc * NN; lb = sm + 16384; }
  else                { gp0 = ATl + z * MAT + (size_t)tc * NN; lb = sm + 24576; }
  f32x4 acc[4][4];
  for (int i = 0; i < 4; ++i)
    for (int j = 0; j < 4; ++j) acc[i][j] = (f32x4){0.f, 0.f, 0.f, 0.f};
  const int swz = (ln & 7);
  for (int kc = 0; kc < NN; kc += 64) {
    __syncthreads();
    const unsigned short* gpk = gp0 + kc + gcol;
    for (int t = 0; t < 16; ++t)
      gload_lds16(gpk + (size_t)(t * 8 + rl) * NN, lb + t * 512);
    __syncthreads();
    for (int ks = 0; ks < 2; ++ks) {
      const int gq = ((ks * 4 + q) ^ swz) << 3;
      bf16x8 fah[4], fal[4], fbh[4], fbl[4];
      for (int i = 0; i < 4; ++i) {
        int off = (wm + i * 16 + ln) * 64 + gq;
        fah[i] = *(const bf16x8*)&sm[off];
        fal[i] = *(const bf16x8*)&sm[8192 + off];
      }
      for (int j = 0; j < 4; ++j) {
        int off = (wn + j * 16 + ln) * 64 + gq;
        fbh[j] = *(const bf16x8*)&sm[16384 + off];
        fbl[j] = *(const bf16x8*)&sm[24576 + off];
      }
      for (int i = 0; i < 4; ++i)
        for (int j = 0; j < 4; ++j) {
          acc[i][j] = __builtin_amdgcn_mfma_f32_16x16x32_bf16(fah[i], fbh[j], acc[i][j], 0, 0, 0);
          acc[i][j] = __builtin_amdgcn_mfma_f32_16x16x32_bf16(fah[i], fbl[j], acc[i][j], 0, 0, 0);
          acc[i][j] = __builtin_amdgcn_mfma_f32_16x16x32_bf16(fal[i], fbh[j], acc[i][j], 0, 0, 0);
        }
    }
  }
  unsigned short* cth = CTh + z * MAT;
  unsigned short* ctl = CTl + z * MAT;
  for (int i = 0; i < 4; ++i) {
    int m0 = tr + wm + i * 16 + q * 4;
    for (int j = 0; j < 4; ++j) {
      int n = tc + wn + j * 16 + ln;
      ushort4 h4, l4;
      unsigned short hs[4], ls[4];
      for (int reg = 0; reg < 4; ++reg) {
        float v = acc[i][j][reg];
        hs[reg] = f2bu(v);
        ls[reg] = f2bu(v - bu2f(hs[reg]));
      }
      h4.x = hs[0]; h4.y = hs[1]; h4.z = hs[2]; h4.w = hs[3];
      l4.x = ls[0]; l4.y = ls[1]; l4.z = ls[2]; l4.w = ls[3];
      *(ushort4*)&cth[(size_t)n * NN + m0] = h4;
      *(ushort4*)&ctl[(size_t)n * NN + m0] = l4;
    }
  }
}

// MFMA GEMM2: P3 = A*C (split bf16), raw f32 out (294-µs proven version)
__global__ void __launch_bounds__(256) k_mm2(
    const unsigned short* __restrict__ Ah, const unsigned short* __restrict__ Al,
    const unsigned short* __restrict__ CTh, const unsigned short* __restrict__ CTl,
    float* __restrict__ S) {
  const int bid = blockIdx.x;
  const int z = bid & 7;
  const int t6 = bid >> 3;
  const int tr = (t6 >> 3) * 128, tc = (t6 & 7) * 128;
  const size_t MAT = (size_t)NN * NN;
  __shared__ unsigned short sm[32768];
  const int tid = threadIdx.x;
  const int wave = tid >> 6, lane = tid & 63;
  const int wm = (wave >> 1) * 64, wn = (wave & 1) * 64;
  const int q = lane >> 4, ln = lane & 15;
  const int rl = lane >> 3;
  const int gcol = ((lane & 7) ^ rl) << 3;
  const unsigned short* gp0;
  unsigned short* lb;
  if (wave == 0)      { gp0 = Ah  + z * MAT + (size_t)tr * NN; lb = sm; }
  else if (wave == 1) { gp0 = Al  + z * MAT + (size_t)tr * NN; lb = sm + 8192; }
  else if (wave == 2) { gp0 = CTh + z * MAT + (size_t)tc * NN; lb = sm + 16384; }
  else                { gp0 = CTl + z * MAT + (size_t)tc * NN; lb = sm + 24576; }
  f32x4 acc[4][4];
  for (int i = 0; i < 4; ++i)
    for (int j = 0; j < 4; ++j) acc[i][j] = (f32x4){0.f, 0.f, 0.f, 0.f};
  const int swz = (ln & 7);
  for (int kc = 0; kc < NN; kc += 64) {
    __syncthreads();
    const unsigned short* gpk = gp0 + kc + gcol;
    for (int t = 0; t < 16; ++t)
      gload_lds16(gpk + (size_t)(t * 8 + rl) * NN, lb + t * 512);
    __syncthreads();
    for (int ks = 0; ks < 2; ++ks) {
      const int gq = ((ks * 4 + q) ^ swz) << 3;
      bf16x8 fah[4], fal[4], fbh[4], fbl[4];
      for (int i = 0; i < 4; ++i) {
        int off = (wm + i * 16 + ln) * 64 + gq;
        fah[i] = *(const bf16x8*)&sm[off];
        fal[i] = *(const bf16x8*)&sm[8192 + off];
      }
      for (int j = 0; j < 4; ++j) {
        int off = (wn + j * 16 + ln) * 64 + gq;
        fbh[j] = *(const bf16x8*)&sm[16384 + off];
        fbl[j] = *(const bf16x8*)&sm[24576 + off];
      }
      for (int i = 0; i < 4; ++i)
        for (int j = 0; j < 4; ++j) {
          acc[i][j] = __builtin_amdgcn_mfma_f32_16x16x32_bf16(fah[i], fbh[j], acc[i][j], 0, 0, 0);
          acc[i][j] = __builtin_amdgcn_mfma_f32_16x16x32_bf16(fah[i], fbl[j], acc[i][j], 0, 0, 0);
          acc[i][j] = __builtin_amdgcn_mfma_f32_16x16x32_bf16(fal[i], fbh[j], acc[i][j], 0, 0, 0);
        }
    }
  }
  float* Sb = S + z * MAT;
  for (int i = 0; i < 4; ++i) {
    int m0 = tr + wm + i * 16 + q * 4;
    for (int j = 0; j < 4; ++j) {
      int n = tc + wn + j * 16 + ln;
      for (int reg = 0; reg < 4; ++reg)
        Sb[(size_t)(m0 + reg) * NN + n] = acc[i][j][reg];
    }
  }
}

// combine + symmetrize, 32x32 pair tiles, single-pass vectorized loads:
// S = 0.5*(T+T^T), T = A + 0.8*C + 0.64*P3 (P3 currently in S). No atomics.
__global__ void __launch_bounds__(256) k_sym3(
    const unsigned short* __restrict__ Ahp, const unsigned short* __restrict__ Alp,
    const unsigned short* __restrict__ CThp, const unsigned short* __restrict__ CTlp,
    float* __restrict__ S) {
  const int z = blockIdx.y;
  const size_t base = (size_t)z * NN * NN;
  int p = blockIdx.x;  // 0..527 -> (ti<=tj)
  int ti = 0, rem = p;
  while (rem >= 32 - ti) {
    rem -= 32 - ti;
    ++ti;
  }
  const int tj = ti + rem;
  const int tid = threadIdx.x;
  const int r = tid >> 3;          // 0..31
  const int c0 = (tid & 7) << 2;   // 0..28
  __shared__ float D1[32][33], D2[32][33];
  __shared__ float E1[32][33], E2[32][33];
  __shared__ float F1[32][33], F2[32][33];
  const size_t i1 = base + (size_t)(ti * 32 + r) * NN + tj * 32 + c0;
  const size_t i2 = base + (size_t)(tj * 32 + r) * NN + ti * 32 + c0;
  {
    float4 d1 = *(const float4*)&S[i1];
    float4 d2 = *(const float4*)&S[i2];
    ushort4 a1h = *(const ushort4*)&Ahp[i1];
    ushort4 a1l = *(const ushort4*)&Alp[i1];
    ushort4 a2h = *(const ushort4*)&Ahp[i2];
    ushort4 a2l = *(const ushort4*)&Alp[i2];
    ushort4 c1h = *(const ushort4*)&CThp[i1];
    ushort4 c1l = *(const ushort4*)&CTlp[i1];
    ushort4 c2h = *(const ushort4*)&CThp[i2];
    ushort4 c2l = *(const ushort4*)&CTlp[i2];
    D1[r][c0] = d1.x; D1[r][c0 + 1] = d1.y; D1[r][c0 + 2] = d1.z; D1[r][c0 + 3] = d1.w;
    D2[r][c0] = d2.x; D2[r][c0 + 1] = d2.y; D2[r][c0 + 2] = d2.z; D2[r][c0 + 3] = d2.w;
    E1[r][c0]     = bu2f(a1h.x) + bu2f(a1l.x);
    E1[r][c0 + 1] = bu2f(a1h.y) + bu2f(a1l.y);
    E1[r][c0 + 2] = bu2f(a1h.z) + bu2f(a1l.z);
    E1[r][c0 + 3] = bu2f(a1h.w) + bu2f(a1l.w);
    E2[r][c0]     = bu2f(a2h.x) + bu2f(a2l.x);
    E2[r][c0 + 1] = bu2f(a2h.y) + bu2f(a2l.y);
    E2[r][c0 + 2] = bu2f(a2h.z) + bu2f(a2l.z);
    E2[r][c0 + 3] = bu2f(a2h.w) + bu2f(a2l.w);
    F1[r][c0]     = bu2f(c1h.x) + bu2f(c1l.x);
    F1[r][c0 + 1] = bu2f(c1h.y) + bu2f(c1l.y);
    F1[r][c0 + 2] = bu2f(c1h.z) + bu2f(c1l.z);
    F1[r][c0 + 3] = bu2f(c1h.w) + bu2f(c1l.w);
    F2[r][c0]     = bu2f(c2h.x) + bu2f(c2l.x);
    F2[r][c0 + 1] = bu2f(c2h.y) + bu2f(c2l.y);
    F2[r][c0 + 2] = bu2f(c2h.z) + bu2f(c2l.z);
    F2[r][c0 + 3] = bu2f(c2h.w) + bu2f(c2l.w);
  }
  __syncthreads();
  float v[4];
  for (int k = 0; k < 4; ++k) {
    int c = c0 + k;
    v[k] = 0.5f * (E1[r][c] + E2[c][r]) + 0.4f * (F2[c][r] + F1[r][c]) +
           0.32f * (D1[r][c] + D2[c][r]);
  }
  // write S[i1] directly
  *(float4*)&S[i1] = make_float4(v[0], v[1], v[2], v[3]);
  // stage v into D1 (all reads done) for transposed S[i2] write
  __syncthreads();
  for (int k = 0; k < 4; ++k) D1[r][c0 + k] = v[k];
  __syncthreads();
  *(float4*)&S[i2] = make_float4(D1[c0][r], D1[c0 + 1][r], D1[c0 + 2][r],
                                 D1[c0 + 3][r]);
}

// thr[b] = min(diag) - mean(diag[:-1] - offdiag)  (294-µs proven)
__global__ void __launch_bounds__(256) k_thr(const float* __restrict__ S,
                                             float* __restrict__ thr) {
  const int b = blockIdx.x;
  const float* Sb = S + (size_t)b * NN * NN;
  const int tid = threadIdx.x;
  float mn = 3.0e38f;
  float rsum = 0.f;
  for (int n = tid; n < NN; n += 256) {
    float d = Sb[(size_t)n * NN + n];
    mn = fminf(mn, d);
    if (n < NN - 1) rsum += d - Sb[(size_t)n * NN + n + 1];
  }
  __shared__ float tmp[4];
  float mtot = blockMinF(mn, tmp);
  float stot = blockSumF(rsum, tmp);
  if (tid == 0) thr[b] = mtot - stot / 1023.0f;
}

__global__ void __launch_bounds__(256) k_stats(const float* __restrict__ S,
                                               const float* __restrict__ thr,
                                               const float* __restrict__ wh1,
                                               const float* __restrict__ wh2,
                                               float* __restrict__ meanv,
                                               float* __restrict__ rstdv) {
  const int n = blockIdx.x;
  const int tid = threadIdx.x;
  double s1 = 0.0, s2 = 0.0;
  for (int b = 0; b < BB; ++b) {
    float t = thr[b];
    float w1 = wh1[b * NN + n];
    const float* Srow = S + ((size_t)b * NN + n) * NN;
    const float* w2p = wh2 + b * NN;
    for (int m = tid; m < NN; m += 256) {
      float e = w1 + w2p[m];
      e = (e > 0.f) ? e : 0.01f * e;
      float att = (Srow[m] > t) ? e : NEGV;
      s1 += (double)att;
      s2 += (double)att * (double)att;
    }
  }
  __shared__ double red[256];
  red[tid] = s1;
  __syncthreads();
  for (int s = 128; s > 0; s >>= 1) {
    if (tid < s) red[tid] += red[tid + s];
    __syncthreads();
  }
  double t1 = red[0];
  __syncthreads();
  red[tid] = s2;
  __syncthreads();
  for (int s = 128; s > 0; s >>= 1) {
    if (tid < s) red[tid] += red[tid + s];
    __syncthreads();
  }
  double t2 = red[0];
  if (tid == 0) {
    double mean = t1 / 8192.0;
    double var = t2 / 8192.0 - mean * mean;
    if (var < 0.0) var = 0.0;
    meanv[n] = (float)mean;
    rstdv[n] = (float)(1.0 / sqrt(var + 1e-5));
  }
}

__global__ void __launch_bounds__(256) k_out(const float* __restrict__ S,
                                             const float* __restrict__ thr,
                                             const float* __restrict__ wh1,
                                             const float* __restrict__ wh2,
                                             const float* __restrict__ meanv,
                                             const float* __restrict__ rstdv,
                                             const float* __restrict__ flag,
                                             void* outv) {
  const int bn = blockIdx.x;
  const int b = bn >> 10;
  const int n = bn & 1023;
  const int tid = threadIdx.x;
  const bool f32m = (flag[0] != 0.0f);
  const float t = thr[b];
  const float w1 = wh1[bn];
  const float* Srow = S + (size_t)bn * NN;
  const float* w2p = wh2 + b * NN;
  float v[4];
  float mx = -3.0e38f;
  for (int w = 0; w < 4; ++w) {
    int m = tid + (w << 8);
    float e = w1 + w2p[m];
    e = (e > 0.f) ? e : 0.01f * e;
    float att = (Srow[m] > t) ? e : NEGV;
    float vv = (att - meanv[n]) * rstdv[n];
    v[w] = vv;
    mx = fmaxf(mx, vv);
  }
  __shared__ float tmp[4];
  float gmx = blockMaxF(mx, tmp);
  float sum = 0.f;
  for (int w = 0; w < 4; ++w) {
    v[w] = __expf(v[w] - gmx);
    sum += v[w];
  }
  float gsum = blockSumF(sum, tmp);
  for (int w = 0; w < 4; ++w) {
    int m = tid + (w << 8);
    float val = v[w] / gsum;
    if (f32m) {
      ((float*)outv)[(size_t)bn * NN + m] = val;
    } else {
      ((bf16*)outv)[(size_t)bn * NN + m] = __float2bfloat16(val);
    }
  }
}

extern "C" void kernel_launch(void* const* d_in, const int* in_sizes, int n_in,
                              void* d_out, int out_size, void* d_ws,
                              size_t ws_size, hipStream_t stream) {
  float* ws = (float*)d_ws;

  float* sq = ws;              // 8192
  float* wh1 = ws + 8192;      // 8192
  float* wh2 = ws + 16384;     // 8192
  float* thr = ws + 24576;     // 8
  float* meanv = ws + 24608;   // 1024
  float* rstdv = ws + 25632;   // 1024
  float* flag = ws + 26656;    // 8
  float* rsum = ws + 26664;    // 8192
  float* h = ws + 65536;       // 524288

  unsigned short* Ah = (unsigned short*)(ws + 589824);
  unsigned short* Al = (unsigned short*)(ws + 4784128);
  unsigned short* ATh = (unsigned short*)(ws + 8978432);
  unsigned short* ATl = (unsigned short*)(ws + 13172736);
  unsigned short* CTh = (unsigned short*)(ws + 17367040);
  unsigned short* CTl = (unsigned short*)(ws + 21561344);
  float* Sf = ws + 25755648;  // 8388608 floats (A_un -> P3 -> S)
  const size_t needed_fast = (25755648ull + 8388608ull) * 4ull;

  if (ws_size < needed_fast) {
    k_fill<<<dim3(2048), 256, 0, stream>>>((unsigned short*)d_out, out_size,
                                           (unsigned short)0xBF80);
    return;
  }

  k_detect<<<dim3(1), 256, 0, stream>>>((const unsigned short*)d_in[0], flag);
  k_h<<<dim3(BB * NN), 64, 0, stream>>>(d_in[0], d_in[1], d_in[2], flag, h, sq,
                                        wh1, wh2);
  k_g<<<dim3(16, 16, BB), 256, 0, stream>>>(h, sq, Sf);
  k_rowsum<<<dim3(BB * NN), 256, 0, stream>>>(Sf, rsum);
  k_split<<<dim3(32, 32, BB), 256, 0, stream>>>(Sf, rsum, Ah, Al, ATh, ATl);
  k_mm1<<<dim3(512), 256, 0, stream>>>(Ah, Al, ATh, ATl, CTh, CTl);
  k_mm2<<<dim3(512), 256, 0, stream>>>(Ah, Al, CTh, CTl, Sf);
  k_sym3<<<dim3(528, BB), 256, 0, stream>>>(Ah, Al, CTh, CTl, Sf);
  k_thr<<<dim3(BB), 256, 0, stream>>>(Sf, thr);
  k_stats<<<dim3(NN), 256, 0, stream>>>(Sf, thr, wh1, wh2, meanv, rstdv);
  k_out<<<dim3(BB * NN), 256, 0, stream>>>(Sf, thr, wh1, wh2, meanv, rstdv,
                                           flag, d_out);
}